// Round 2
// baseline (2190.830 us; speedup 1.0000x reference)
//
#include <hip/hip_runtime.h>

// Problem constants (B, D, H, O, T, NOPS from reference)
static constexpr int Bn = 8192;
static constexpr int Dd = 1024;
static constexpr int Hh = 2048;
static constexpr int Oo = 1024;
static constexpr int Tt = 4;
static constexpr int NO = 3;
#define TB 256

typedef __attribute__((ext_vector_type(8))) short bf16x8;
typedef __attribute__((ext_vector_type(4))) float f32x4;

__device__ __forceinline__ ushort f2bf(float f) {
  union { float f; unsigned u; } v; v.f = f;
  return (ushort)((v.u + 0x7FFFu + ((v.u >> 16) & 1u)) >> 16);  // RNE
}

// Top-2 of logits per temper (softmax is monotonic; jax top_k ties -> lower idx).
__global__ void top2_kernel(const float* __restrict__ logits, int* __restrict__ idx) {
  if (threadIdx.x == 0 && blockIdx.x == 0) {
    for (int t = 0; t < Tt; ++t) {
      const float* lg = logits + t * NO;
      int i0 = 0;
      for (int k = 1; k < NO; ++k) if (lg[k] > lg[i0]) i0 = k;
      int i1 = -1;
      for (int k = 0; k < NO; ++k) {
        if (k == i0) continue;
        if (i1 < 0 || lg[k] > lg[i1]) i1 = k;
      }
      idx[2 * t] = i0;
      idx[2 * t + 1] = i1;
    }
  }
}

__global__ void cvt_bf16(const float* __restrict__ src, ushort* __restrict__ dst, int n4) {
  int i = blockIdx.x * blockDim.x + threadIdx.x;
  if (i >= n4) return;
  float4 v = ((const float4*)src)[i];
  ((ushort4*)dst)[i] = make_ushort4(f2bf(v.x), f2bf(v.y), f2bf(v.z), f2bf(v.w));
}

// Convert the two routed operator weight matrices (indices live on device).
__global__ void cvt_sel(const float* __restrict__ WopT, const int* __restrict__ idx2,
                        ushort* __restrict__ Wa, ushort* __restrict__ Wb, int n4) {
  int i = blockIdx.x * blockDim.x + threadIdx.x;
  if (i >= n4) return;
  size_t n = (size_t)n4 * 4;
  float4 va = ((const float4*)(WopT + (size_t)idx2[0] * n))[i];
  float4 vb = ((const float4*)(WopT + (size_t)idx2[1] * n))[i];
  ((ushort4*)Wa)[i] = make_ushort4(f2bf(va.x), f2bf(va.y), f2bf(va.z), f2bf(va.w));
  ((ushort4*)Wb)[i] = make_ushort4(f2bf(vb.x), f2bf(vb.y), f2bf(vb.z), f2bf(vb.w));
}

// C[M,N] = A[M,K] @ B[N,K]^T, bf16 in, fp32 accumulate.
// EP 0: C(bf16) = relu(acc + bias[col])   (bias optionally indirected via idxp)
// EP 1: C(f32)  = acc + bias[col]
// EP 2: C(f32) += acc
// 128x128 tile, BK=32, 4 waves each computing 4x4 of 16x16x32 MFMA tiles.
//
// LDS layout (conflict-free reads): chunk c (16B) holds
//   global row = (c>>6)*16 + (c&15), k-chunk = (c>>4)&3  (8 bf16 each).
// Fragment read for (i, quad, l16) is then chunk (wm/16+i)*64 + quad*16 + l16,
// i.e. byte offset lane*16 within the wave -> contiguous, zero bank conflicts.
template <int EP>
__global__ __launch_bounds__(TB) void gemm_bt(
    const ushort* __restrict__ A, int lda,
    const ushort* __restrict__ B, int ldb,
    const float* __restrict__ bias, const int* __restrict__ idxp, int sel, int bstride,
    void* __restrict__ Cv, int ldc, int K) {
  __shared__ __align__(16) ushort As[128 * 32];
  __shared__ __align__(16) ushort Bs[128 * 32];
  const int tid = threadIdx.x;
  const int w = tid >> 6;
  const int lane = tid & 63;
  const int quad = lane >> 4;
  const int l16 = lane & 15;
  const int m0 = blockIdx.y * 128;
  const int n0 = blockIdx.x * 128;
  const int wm = (w >> 1) * 64;  // wave's 64x64 sub-tile
  const int wn = (w & 1) * 64;

  f32x4 acc[4][4];
#pragma unroll
  for (int i = 0; i < 4; ++i)
#pragma unroll
    for (int j = 0; j < 4; ++j)
#pragma unroll
      for (int r = 0; r < 4; ++r) acc[i][j][r] = 0.f;

  // Staging: thread t stages chunks c=t and c=t+256 (rows +64).
  // Global source for chunk c per the LDS layout above.
  const int srow = ((tid >> 6) << 4) + (tid & 15);
  const int skc = ((tid >> 4) & 3) * 8;
  const ushort* a0 = A + (size_t)(m0 + srow) * lda + skc;
  const ushort* a1 = A + (size_t)(m0 + 64 + srow) * lda + skc;
  const ushort* b0 = B + (size_t)(n0 + srow) * ldb + skc;
  const ushort* b1 = B + (size_t)(n0 + 64 + srow) * ldb + skc;
  ushort* lA0 = As + w * 512;
  ushort* lA1 = As + 2048 + w * 512;
  ushort* lB0 = Bs + w * 512;
  ushort* lB1 = Bs + 2048 + w * 512;

  for (int kk = 0; kk < K; kk += 32) {
    __builtin_amdgcn_global_load_lds((const __attribute__((address_space(1))) void*)(a0 + kk),
                                     (__attribute__((address_space(3))) void*)lA0, 16, 0, 0);
    __builtin_amdgcn_global_load_lds((const __attribute__((address_space(1))) void*)(a1 + kk),
                                     (__attribute__((address_space(3))) void*)lA1, 16, 0, 0);
    __builtin_amdgcn_global_load_lds((const __attribute__((address_space(1))) void*)(b0 + kk),
                                     (__attribute__((address_space(3))) void*)lB0, 16, 0, 0);
    __builtin_amdgcn_global_load_lds((const __attribute__((address_space(1))) void*)(b1 + kk),
                                     (__attribute__((address_space(3))) void*)lB1, 16, 0, 0);
    __syncthreads();  // drains vmcnt -> LDS tiles valid

    bf16x8 af[4], bfr[4];
#pragma unroll
    for (int i = 0; i < 4; ++i)
      af[i] = *(const bf16x8*)&As[((wm >> 4) + i) * 512 + quad * 128 + l16 * 8];
#pragma unroll
    for (int j = 0; j < 4; ++j)
      bfr[j] = *(const bf16x8*)&Bs[((wn >> 4) + j) * 512 + quad * 128 + l16 * 8];
#pragma unroll
    for (int i = 0; i < 4; ++i)
#pragma unroll
      for (int j = 0; j < 4; ++j)
        acc[i][j] = __builtin_amdgcn_mfma_f32_16x16x32_bf16(af[i], bfr[j], acc[i][j], 0, 0, 0);
    __syncthreads();  // LDS reuse next iter
  }

  const float* bb = bias;
  if (EP == 0 && idxp) bb += (size_t)idxp[sel] * bstride;

  // C/D layout: col = lane&15, row = quad*4 + r  (verified mapping)
#pragma unroll
  for (int i = 0; i < 4; ++i) {
#pragma unroll
    for (int j = 0; j < 4; ++j) {
      const int col = n0 + wn + j * 16 + l16;
      const float bv = (EP == 2) ? 0.f : bb[col];
#pragma unroll
      for (int r = 0; r < 4; ++r) {
        const int row = m0 + wm + i * 16 + quad * 4 + r;
        float v = acc[i][j][r] + bv;
        if (EP == 0) {
          v = v > 0.f ? v : 0.f;
          ((ushort*)Cv)[(size_t)row * ldc + col] = f2bf(v);
        } else if (EP == 1) {
          ((float*)Cv)[(size_t)row * ldc + col] = v;
        } else {
          ((float*)Cv)[(size_t)row * ldc + col] += v;
        }
      }
    }
  }
}

extern "C" void kernel_launch(void* const* d_in, const int* in_sizes, int n_in,
                              void* d_out, int out_size, void* d_ws, size_t ws_size,
                              hipStream_t stream) {
  const float* x      = (const float*)d_in[0];
  const float* Wp     = (const float*)d_in[1];
  const float* bp     = (const float*)d_in[2];
  const float* Wop    = (const float*)d_in[3];
  const float* bop    = (const float*)d_in[4];
  const float* logits = (const float*)d_in[5];
  const float* Wr     = (const float*)d_in[6];
  const float* br     = (const float*)d_in[7];
  float* out = (float*)d_out;

  // Workspace layout (~128.25 MB total)
  char* ws = (char*)d_ws;
  size_t off = 0;
  int* idx = (int*)ws;                          off += 256;
  ushort* xb   = (ushort*)(ws + off);           off += (size_t)Bn * Dd * 2;        // 16 MB
  ushort* WpB  = (ushort*)(ws + off);           off += (size_t)Tt * Hh * Dd * 2;   // 16 MB
  ushort* WrB  = (ushort*)(ws + off);           off += (size_t)Oo * Tt * Hh * 2;   // 16 MB
  ushort* WaB  = (ushort*)(ws + off);           off += (size_t)Hh * Hh * 2;        // 8 MB
  ushort* WbB  = (ushort*)(ws + off);           off += (size_t)Hh * Hh * 2;        // 8 MB
  ushort* bufA = (ushort*)(ws + off);           off += (size_t)Bn * Hh * 2;        // 32 MB
  ushort* bufB = (ushort*)(ws + off);           off += (size_t)Bn * Hh * 2;        // 32 MB

  top2_kernel<<<1, 64, 0, stream>>>(logits, idx);
  {
    int n4 = Bn * Dd / 4;
    cvt_bf16<<<(n4 + TB - 1) / TB, TB, 0, stream>>>(x, xb, n4);
  }
  {
    int n4 = Tt * Hh * Dd / 4;
    cvt_bf16<<<(n4 + TB - 1) / TB, TB, 0, stream>>>(Wp, WpB, n4);
  }
  {
    int n4 = Oo * Tt * Hh / 4;
    cvt_bf16<<<(n4 + TB - 1) / TB, TB, 0, stream>>>(Wr, WrB, n4);
  }

  dim3 gHB(Hh / 128, Bn / 128);  // N=2048 GEMMs
  dim3 gOB(Oo / 128, Bn / 128);  // readout N=1024

  for (int t = 0; t < Tt; ++t) {
    int n4 = Hh * Hh / 4;
    cvt_sel<<<(n4 + TB - 1) / TB, TB, 0, stream>>>(Wop + (size_t)t * NO * Hh * Hh, idx + 2 * t,
                                                   WaB, WbB, n4);
    // a1 = relu(x @ Wp_t^T + bp_t)               [B,H] bf16
    gemm_bt<0><<<gHB, TB, 0, stream>>>(xb, Dd, WpB + (size_t)t * Hh * Dd, Dd,
                                       bp + (size_t)t * Hh, nullptr, 0, 0, bufA, Hh, Dd);
    // h  = relu(a1 @ Wa^T + ba)                  [B,H] bf16
    gemm_bt<0><<<gHB, TB, 0, stream>>>(bufA, Hh, WaB, Hh,
                                       bop + (size_t)t * NO * Hh, idx + 2 * t, 0, Hh,
                                       bufB, Hh, Hh);
    // o  = relu(h @ Wb^T + bb)                   [B,H] bf16 (double relu collapses)
    gemm_bt<0><<<gHB, TB, 0, stream>>>(bufB, Hh, WbB, Hh,
                                       bop + (size_t)t * NO * Hh, idx + 2 * t, 1, Hh,
                                       bufA, Hh, Hh);
    // out (+)= o @ Wr[:, t*H:(t+1)*H]^T  (+ br at t=0)
    if (t == 0)
      gemm_bt<1><<<gOB, TB, 0, stream>>>(bufA, Hh, WrB + (size_t)t * Hh, Tt * Hh,
                                         br, nullptr, 0, 0, out, Oo, Hh);
    else
      gemm_bt<2><<<gOB, TB, 0, stream>>>(bufA, Hh, WrB + (size_t)t * Hh, Tt * Hh,
                                         nullptr, nullptr, 0, 0, out, Oo, Hh);
  }
}

// Round 3
// 1679.606 us; speedup vs baseline: 1.3044x; 1.3044x over previous
//
#include <hip/hip_runtime.h>

// Problem constants (B, D, H, O, T, NOPS from reference)
static constexpr int Bn = 8192;
static constexpr int Dd = 1024;
static constexpr int Hh = 2048;
static constexpr int Oo = 1024;
static constexpr int Tt = 4;
static constexpr int NO = 3;
#define TB 256

typedef __attribute__((ext_vector_type(8))) short bf16x8;
typedef __attribute__((ext_vector_type(4))) float f32x4;

__device__ __forceinline__ ushort f2bf(float f) {
  union { float f; unsigned u; } v; v.f = f;
  return (ushort)((v.u + 0x7FFFu + ((v.u >> 16) & 1u)) >> 16);  // RNE
}

// Top-2 of logits per temper (softmax is monotonic; jax top_k ties -> lower idx).
__global__ void top2_kernel(const float* __restrict__ logits, int* __restrict__ idx) {
  if (threadIdx.x == 0 && blockIdx.x == 0) {
    for (int t = 0; t < Tt; ++t) {
      const float* lg = logits + t * NO;
      int i0 = 0;
      for (int k = 1; k < NO; ++k) if (lg[k] > lg[i0]) i0 = k;
      int i1 = -1;
      for (int k = 0; k < NO; ++k) {
        if (k == i0) continue;
        if (i1 < 0 || lg[k] > lg[i1]) i1 = k;
      }
      idx[2 * t] = i0;
      idx[2 * t + 1] = i1;
    }
  }
}

__global__ void cvt_bf16(const float* __restrict__ src, ushort* __restrict__ dst, int n4) {
  int i = blockIdx.x * blockDim.x + threadIdx.x;
  if (i >= n4) return;
  float4 v = ((const float4*)src)[i];
  ((ushort4*)dst)[i] = make_ushort4(f2bf(v.x), f2bf(v.y), f2bf(v.z), f2bf(v.w));
}

// Convert the two routed operator weight matrices (indices live on device).
__global__ void cvt_sel(const float* __restrict__ WopT, const int* __restrict__ idx2,
                        ushort* __restrict__ Wa, ushort* __restrict__ Wb, int n4) {
  int i = blockIdx.x * blockDim.x + threadIdx.x;
  if (i >= n4) return;
  size_t n = (size_t)n4 * 4;
  float4 va = ((const float4*)(WopT + (size_t)idx2[0] * n))[i];
  float4 vb = ((const float4*)(WopT + (size_t)idx2[1] * n))[i];
  ((ushort4*)Wa)[i] = make_ushort4(f2bf(va.x), f2bf(va.y), f2bf(va.z), f2bf(va.w));
  ((ushort4*)Wb)[i] = make_ushort4(f2bf(vb.x), f2bf(vb.y), f2bf(vb.z), f2bf(vb.w));
}

// C[M,N] = A[M,K] @ B[N,K]^T, bf16 in, fp32 accumulate.
// EP 0: C(bf16) = relu(acc + bias[col])   (bias optionally indirected via idxp)
// EP 1: C(f32)  = acc + bias[col]
// EP 2: C(f32) += acc
// 128x128 tile, BK=32, 4 waves each computing 4x4 of 16x16x32 MFMA tiles.
//
// Staging (XOR swizzle — coalesced globals AND conflict-free LDS reads):
//   lane i stages global (row = i>>2, kchunk = (i&3) ^ ((i>>3)&3)) into LDS
//   chunk i (16B). 4-lane groups still read one contiguous 64B row segment
//   (round-1 coalescing). Fragment read (quad q, row l16) hits chunk
//   l16*4 + (q ^ ((l16>>1)&3)): 8 consecutive lanes cover all 32 banks once;
//   16 lanes alias 2-way (free per m136).
template <int EP>
__global__ __launch_bounds__(TB) void gemm_bt(
    const ushort* __restrict__ A, int lda,
    const ushort* __restrict__ B, int ldb,
    const float* __restrict__ bias, const int* __restrict__ idxp, int sel, int bstride,
    void* __restrict__ Cv, int ldc, int K) {
  __shared__ __align__(16) ushort As[128 * 32];
  __shared__ __align__(16) ushort Bs[128 * 32];
  const int tid = threadIdx.x;
  const int w = tid >> 6;
  const int lane = tid & 63;
  const int quad = lane >> 4;
  const int l16 = lane & 15;
  const int m0 = blockIdx.y * 128;
  const int n0 = blockIdx.x * 128;
  const int wm = (w >> 1) * 64;  // wave's 64x64 sub-tile
  const int wn = (w & 1) * 64;

  f32x4 acc[4][4];
#pragma unroll
  for (int i = 0; i < 4; ++i)
#pragma unroll
    for (int j = 0; j < 4; ++j)
#pragma unroll
      for (int r = 0; r < 4; ++r) acc[i][j][r] = 0.f;

  // Staging addresses (see header comment).
  const int srow = tid >> 2;
  const int skc = ((tid & 3) ^ ((tid >> 3) & 3)) * 8;
  const ushort* a0 = A + (size_t)(m0 + srow) * lda + skc;
  const ushort* a1 = A + (size_t)(m0 + 64 + srow) * lda + skc;
  const ushort* b0 = B + (size_t)(n0 + srow) * ldb + skc;
  const ushort* b1 = B + (size_t)(n0 + 64 + srow) * ldb + skc;
  ushort* lA0 = As + w * 512;
  ushort* lA1 = As + 2048 + w * 512;
  ushort* lB0 = Bs + w * 512;
  ushort* lB1 = Bs + 2048 + w * 512;

  // Fragment LDS indices (swizzled k-chunk), invariant across i/tiles.
  const int fq = (quad ^ ((l16 >> 1) & 3)) * 8;

  for (int kk = 0; kk < K; kk += 32) {
    __builtin_amdgcn_global_load_lds((const __attribute__((address_space(1))) void*)(a0 + kk),
                                     (__attribute__((address_space(3))) void*)lA0, 16, 0, 0);
    __builtin_amdgcn_global_load_lds((const __attribute__((address_space(1))) void*)(a1 + kk),
                                     (__attribute__((address_space(3))) void*)lA1, 16, 0, 0);
    __builtin_amdgcn_global_load_lds((const __attribute__((address_space(1))) void*)(b0 + kk),
                                     (__attribute__((address_space(3))) void*)lB0, 16, 0, 0);
    __builtin_amdgcn_global_load_lds((const __attribute__((address_space(1))) void*)(b1 + kk),
                                     (__attribute__((address_space(3))) void*)lB1, 16, 0, 0);
    __syncthreads();  // drains vmcnt -> LDS tiles valid

    bf16x8 af[4], bfr[4];
#pragma unroll
    for (int i = 0; i < 4; ++i)
      af[i] = *(const bf16x8*)&As[((wm >> 4) + i) * 512 + l16 * 32 + fq];
#pragma unroll
    for (int j = 0; j < 4; ++j)
      bfr[j] = *(const bf16x8*)&Bs[((wn >> 4) + j) * 512 + l16 * 32 + fq];
#pragma unroll
    for (int i = 0; i < 4; ++i)
#pragma unroll
      for (int j = 0; j < 4; ++j)
        acc[i][j] = __builtin_amdgcn_mfma_f32_16x16x32_bf16(af[i], bfr[j], acc[i][j], 0, 0, 0);
    __syncthreads();  // LDS reuse next iter
  }

  const float* bb = bias;
  if (EP == 0 && idxp) bb += (size_t)idxp[sel] * bstride;

  // C/D layout: col = lane&15, row = quad*4 + r  (verified mapping)
#pragma unroll
  for (int i = 0; i < 4; ++i) {
#pragma unroll
    for (int j = 0; j < 4; ++j) {
      const int col = n0 + wn + j * 16 + l16;
      const float bv = (EP == 2) ? 0.f : bb[col];
#pragma unroll
      for (int r = 0; r < 4; ++r) {
        const int row = m0 + wm + i * 16 + quad * 4 + r;
        float v = acc[i][j][r] + bv;
        if (EP == 0) {
          v = v > 0.f ? v : 0.f;
          ((ushort*)Cv)[(size_t)row * ldc + col] = f2bf(v);
        } else if (EP == 1) {
          ((float*)Cv)[(size_t)row * ldc + col] = v;
        } else {
          ((float*)Cv)[(size_t)row * ldc + col] += v;
        }
      }
    }
  }
}

extern "C" void kernel_launch(void* const* d_in, const int* in_sizes, int n_in,
                              void* d_out, int out_size, void* d_ws, size_t ws_size,
                              hipStream_t stream) {
  const float* x      = (const float*)d_in[0];
  const float* Wp     = (const float*)d_in[1];
  const float* bp     = (const float*)d_in[2];
  const float* Wop    = (const float*)d_in[3];
  const float* bop    = (const float*)d_in[4];
  const float* logits = (const float*)d_in[5];
  const float* Wr     = (const float*)d_in[6];
  const float* br     = (const float*)d_in[7];
  float* out = (float*)d_out;

  // Workspace layout (~128.25 MB total)
  char* ws = (char*)d_ws;
  size_t off = 0;
  int* idx = (int*)ws;                          off += 256;
  ushort* xb   = (ushort*)(ws + off);           off += (size_t)Bn * Dd * 2;        // 16 MB
  ushort* WpB  = (ushort*)(ws + off);           off += (size_t)Tt * Hh * Dd * 2;   // 16 MB
  ushort* WrB  = (ushort*)(ws + off);           off += (size_t)Oo * Tt * Hh * 2;   // 16 MB
  ushort* WaB  = (ushort*)(ws + off);           off += (size_t)Hh * Hh * 2;        // 8 MB
  ushort* WbB  = (ushort*)(ws + off);           off += (size_t)Hh * Hh * 2;        // 8 MB
  ushort* bufA = (ushort*)(ws + off);           off += (size_t)Bn * Hh * 2;        // 32 MB
  ushort* bufB = (ushort*)(ws + off);           off += (size_t)Bn * Hh * 2;        // 32 MB

  top2_kernel<<<1, 64, 0, stream>>>(logits, idx);
  {
    int n4 = Bn * Dd / 4;
    cvt_bf16<<<(n4 + TB - 1) / TB, TB, 0, stream>>>(x, xb, n4);
  }
  {
    int n4 = Tt * Hh * Dd / 4;
    cvt_bf16<<<(n4 + TB - 1) / TB, TB, 0, stream>>>(Wp, WpB, n4);
  }
  {
    int n4 = Oo * Tt * Hh / 4;
    cvt_bf16<<<(n4 + TB - 1) / TB, TB, 0, stream>>>(Wr, WrB, n4);
  }

  dim3 gHB(Hh / 128, Bn / 128);  // N=2048 GEMMs
  dim3 gOB(Oo / 128, Bn / 128);  // readout N=1024

  for (int t = 0; t < Tt; ++t) {
    int n4 = Hh * Hh / 4;
    cvt_sel<<<(n4 + TB - 1) / TB, TB, 0, stream>>>(Wop + (size_t)t * NO * Hh * Hh, idx + 2 * t,
                                                   WaB, WbB, n4);
    // a1 = relu(x @ Wp_t^T + bp_t)               [B,H] bf16
    gemm_bt<0><<<gHB, TB, 0, stream>>>(xb, Dd, WpB + (size_t)t * Hh * Dd, Dd,
                                       bp + (size_t)t * Hh, nullptr, 0, 0, bufA, Hh, Dd);
    // h  = relu(a1 @ Wa^T + ba)                  [B,H] bf16
    gemm_bt<0><<<gHB, TB, 0, stream>>>(bufA, Hh, WaB, Hh,
                                       bop + (size_t)t * NO * Hh, idx + 2 * t, 0, Hh,
                                       bufB, Hh, Hh);
    // o  = relu(h @ Wb^T + bb)                   [B,H] bf16 (double relu collapses)
    gemm_bt<0><<<gHB, TB, 0, stream>>>(bufB, Hh, WbB, Hh,
                                       bop + (size_t)t * NO * Hh, idx + 2 * t, 1, Hh,
                                       bufA, Hh, Hh);
    // out (+)= o @ Wr[:, t*H:(t+1)*H]^T  (+ br at t=0)
    if (t == 0)
      gemm_bt<1><<<gOB, TB, 0, stream>>>(bufA, Hh, WrB + (size_t)t * Hh, Tt * Hh,
                                         br, nullptr, 0, 0, out, Oo, Hh);
    else
      gemm_bt<2><<<gOB, TB, 0, stream>>>(bufA, Hh, WrB + (size_t)t * Hh, Tt * Hh,
                                         nullptr, nullptr, 0, 0, out, Oo, Hh);
  }
}

// Round 4
// 1467.251 us; speedup vs baseline: 1.4932x; 1.1447x over previous
//
#include <hip/hip_runtime.h>

// Problem constants (B, D, H, O, T, NOPS from reference)
static constexpr int Bn = 8192;
static constexpr int Dd = 1024;
static constexpr int Hh = 2048;
static constexpr int Oo = 1024;
static constexpr int Tt = 4;
static constexpr int NO = 3;
#define TB 256

typedef __attribute__((ext_vector_type(8))) short bf16x8;
typedef __attribute__((ext_vector_type(4))) float f32x4;

__device__ __forceinline__ ushort f2bf(float f) {
  union { float f; unsigned u; } v; v.f = f;
  return (ushort)((v.u + 0x7FFFu + ((v.u >> 16) & 1u)) >> 16);  // RNE
}

// Top-2 of logits per temper (softmax is monotonic; jax top_k ties -> lower idx).
__global__ void top2_kernel(const float* __restrict__ logits, int* __restrict__ idx) {
  if (threadIdx.x == 0 && blockIdx.x == 0) {
    for (int t = 0; t < Tt; ++t) {
      const float* lg = logits + t * NO;
      int i0 = 0;
      for (int k = 1; k < NO; ++k) if (lg[k] > lg[i0]) i0 = k;
      int i1 = -1;
      for (int k = 0; k < NO; ++k) {
        if (k == i0) continue;
        if (i1 < 0 || lg[k] > lg[i1]) i1 = k;
      }
      idx[2 * t] = i0;
      idx[2 * t + 1] = i1;
    }
  }
}

__global__ void cvt_bf16(const float* __restrict__ src, ushort* __restrict__ dst, int n4) {
  int i = blockIdx.x * blockDim.x + threadIdx.x;
  if (i >= n4) return;
  float4 v = ((const float4*)src)[i];
  ((ushort4*)dst)[i] = make_ushort4(f2bf(v.x), f2bf(v.y), f2bf(v.z), f2bf(v.w));
}

// Convert the two routed operator weight matrices (indices live on device).
__global__ void cvt_sel(const float* __restrict__ WopT, const int* __restrict__ idx2,
                        ushort* __restrict__ Wa, ushort* __restrict__ Wb, int n4) {
  int i = blockIdx.x * blockDim.x + threadIdx.x;
  if (i >= n4) return;
  size_t n = (size_t)n4 * 4;
  float4 va = ((const float4*)(WopT + (size_t)idx2[0] * n))[i];
  float4 vb = ((const float4*)(WopT + (size_t)idx2[1] * n))[i];
  ((ushort4*)Wa)[i] = make_ushort4(f2bf(va.x), f2bf(va.y), f2bf(va.z), f2bf(va.w));
  ((ushort4*)Wb)[i] = make_ushort4(f2bf(vb.x), f2bf(vb.y), f2bf(vb.z), f2bf(vb.w));
}

#define ISSUE_TILE(kk, p)                                                                   \
  do {                                                                                      \
    __builtin_amdgcn_global_load_lds(                                                       \
        (const __attribute__((address_space(1))) void*)(a0 + (kk)),                         \
        (__attribute__((address_space(3))) void*)(&As[p][w * 512]), 16, 0, 0);              \
    __builtin_amdgcn_global_load_lds(                                                       \
        (const __attribute__((address_space(1))) void*)(a1 + (kk)),                         \
        (__attribute__((address_space(3))) void*)(&As[p][2048 + w * 512]), 16, 0, 0);       \
    __builtin_amdgcn_global_load_lds(                                                       \
        (const __attribute__((address_space(1))) void*)(b0 + (kk)),                         \
        (__attribute__((address_space(3))) void*)(&Bs[p][w * 512]), 16, 0, 0);              \
    __builtin_amdgcn_global_load_lds(                                                       \
        (const __attribute__((address_space(1))) void*)(b1 + (kk)),                         \
        (__attribute__((address_space(3))) void*)(&Bs[p][2048 + w * 512]), 16, 0, 0);       \
  } while (0)

// C[M,N] = A[M,K] @ B[N,K]^T, bf16 in, fp32 accumulate.
// EP 0: C(bf16) = relu(acc + bias[col]); EP 1: C(f32) = acc + bias; EP 2: C(f32) += acc
// 128x128 tile, BK=32, 4 waves x (4x4 of 16x16x32 MFMA).
// Double-buffered LDS: ONE barrier/iter; prefetch k+1 issued right after the
// barrier validating k, in flight during compute of k (hides L2/L3 latency).
// XOR-swizzled staging: coalesced globals + conflict-free LDS reads (R3).
// XCD patch swizzle: f%8 -> XCD owns an 8x16-tile patch of C (B-strip fits L2).
template <int EP>
__global__ __launch_bounds__(TB) void gemm_bt(
    const ushort* __restrict__ A, int lda,
    const ushort* __restrict__ B, int ldb,
    const float* __restrict__ bias, const int* __restrict__ idxp, int sel, int bstride,
    void* __restrict__ Cv, int ldc, int K) {
  __shared__ __align__(16) ushort As[2][128 * 32];
  __shared__ __align__(16) ushort Bs[2][128 * 32];
  const int tid = threadIdx.x;
  const int w = tid >> 6;
  const int lane = tid & 63;
  const int quad = lane >> 4;
  const int l16 = lane & 15;

  // XCD-aware block remap (speed heuristic only; any mapping is correct).
  const int GX = gridDim.x, GY = gridDim.y;
  const int f = blockIdx.y * GX + blockIdx.x;
  const int xcd = f & 7;
  const int s = f >> 3;
  const int pxc = (GX >= 16) ? 2 : 1;     // patch grid: pxc x (8/pxc)
  const int pw = GX / pxc;                // patch width (tiles)
  const int ph = (GY * pxc) >> 3;         // patch height (tiles)
  const int bx = (xcd % pxc) * pw + (s % pw);
  const int by = (xcd / pxc) * ph + (s / pw);
  const int m0 = by * 128;
  const int n0 = bx * 128;
  const int wm = (w >> 1) * 64;  // wave's 64x64 sub-tile
  const int wn = (w & 1) * 64;

  f32x4 acc[4][4];
#pragma unroll
  for (int i = 0; i < 4; ++i)
#pragma unroll
    for (int j = 0; j < 4; ++j)
#pragma unroll
      for (int r = 0; r < 4; ++r) acc[i][j][r] = 0.f;

  // Staging: lane i -> global (row=i>>2, kchunk=(i&3)^((i>>3)&3)), LDS chunk i.
  const int srow = tid >> 2;
  const int skc = ((tid & 3) ^ ((tid >> 3) & 3)) * 8;
  const ushort* a0 = A + (size_t)(m0 + srow) * lda + skc;
  const ushort* a1 = A + (size_t)(m0 + 64 + srow) * lda + skc;
  const ushort* b0 = B + (size_t)(n0 + srow) * ldb + skc;
  const ushort* b1 = B + (size_t)(n0 + 64 + srow) * ldb + skc;

  // Fragment LDS k-chunk swizzle, invariant across tiles.
  const int fq = (quad ^ ((l16 >> 1) & 3)) * 8;

  const int niter = K >> 5;
  ISSUE_TILE(0, 0);
  for (int it = 0; it < niter; ++it) {
    const int p = it & 1;
    __syncthreads();  // drains vmcnt -> buf p valid; buf p^1 free for prefetch
    if (it + 1 < niter) ISSUE_TILE((it + 1) << 5, p ^ 1);

    bf16x8 af[4], bfr[4];
#pragma unroll
    for (int i = 0; i < 4; ++i)
      af[i] = *(const bf16x8*)&As[p][((wm >> 4) + i) * 512 + l16 * 32 + fq];
#pragma unroll
    for (int j = 0; j < 4; ++j)
      bfr[j] = *(const bf16x8*)&Bs[p][((wn >> 4) + j) * 512 + l16 * 32 + fq];
#pragma unroll
    for (int i = 0; i < 4; ++i)
#pragma unroll
      for (int j = 0; j < 4; ++j)
        acc[i][j] = __builtin_amdgcn_mfma_f32_16x16x32_bf16(af[i], bfr[j], acc[i][j], 0, 0, 0);
  }

  const float* bb = bias;
  if (EP == 0 && idxp) bb += (size_t)idxp[sel] * bstride;

  // C/D layout: col = lane&15, row = quad*4 + r  (verified mapping)
#pragma unroll
  for (int i = 0; i < 4; ++i) {
#pragma unroll
    for (int j = 0; j < 4; ++j) {
      const int col = n0 + wn + j * 16 + l16;
      const float bv = (EP == 2) ? 0.f : bb[col];
#pragma unroll
      for (int r = 0; r < 4; ++r) {
        const int row = m0 + wm + i * 16 + quad * 4 + r;
        float v = acc[i][j][r] + bv;
        if (EP == 0) {
          v = v > 0.f ? v : 0.f;
          ((ushort*)Cv)[(size_t)row * ldc + col] = f2bf(v);
        } else if (EP == 1) {
          ((float*)Cv)[(size_t)row * ldc + col] = v;
        } else {
          ((float*)Cv)[(size_t)row * ldc + col] += v;
        }
      }
    }
  }
}

extern "C" void kernel_launch(void* const* d_in, const int* in_sizes, int n_in,
                              void* d_out, int out_size, void* d_ws, size_t ws_size,
                              hipStream_t stream) {
  const float* x      = (const float*)d_in[0];
  const float* Wp     = (const float*)d_in[1];
  const float* bp     = (const float*)d_in[2];
  const float* Wop    = (const float*)d_in[3];
  const float* bop    = (const float*)d_in[4];
  const float* logits = (const float*)d_in[5];
  const float* Wr     = (const float*)d_in[6];
  const float* br     = (const float*)d_in[7];
  float* out = (float*)d_out;

  // Workspace layout (~128.25 MB total)
  char* ws = (char*)d_ws;
  size_t off = 0;
  int* idx = (int*)ws;                          off += 256;
  ushort* xb   = (ushort*)(ws + off);           off += (size_t)Bn * Dd * 2;        // 16 MB
  ushort* WpB  = (ushort*)(ws + off);           off += (size_t)Tt * Hh * Dd * 2;   // 16 MB
  ushort* WrB  = (ushort*)(ws + off);           off += (size_t)Oo * Tt * Hh * 2;   // 16 MB
  ushort* WaB  = (ushort*)(ws + off);           off += (size_t)Hh * Hh * 2;        // 8 MB
  ushort* WbB  = (ushort*)(ws + off);           off += (size_t)Hh * Hh * 2;        // 8 MB
  ushort* bufA = (ushort*)(ws + off);           off += (size_t)Bn * Hh * 2;        // 32 MB
  ushort* bufB = (ushort*)(ws + off);           off += (size_t)Bn * Hh * 2;        // 32 MB

  top2_kernel<<<1, 64, 0, stream>>>(logits, idx);
  {
    int n4 = Bn * Dd / 4;
    cvt_bf16<<<(n4 + TB - 1) / TB, TB, 0, stream>>>(x, xb, n4);
  }
  {
    int n4 = Tt * Hh * Dd / 4;
    cvt_bf16<<<(n4 + TB - 1) / TB, TB, 0, stream>>>(Wp, WpB, n4);
  }
  {
    int n4 = Oo * Tt * Hh / 4;
    cvt_bf16<<<(n4 + TB - 1) / TB, TB, 0, stream>>>(Wr, WrB, n4);
  }

  dim3 gHB(Hh / 128, Bn / 128);  // N=2048 GEMMs
  dim3 gOB(Oo / 128, Bn / 128);  // readout N=1024

  for (int t = 0; t < Tt; ++t) {
    int n4 = Hh * Hh / 4;
    cvt_sel<<<(n4 + TB - 1) / TB, TB, 0, stream>>>(Wop + (size_t)t * NO * Hh * Hh, idx + 2 * t,
                                                   WaB, WbB, n4);
    // a1 = relu(x @ Wp_t^T + bp_t)               [B,H] bf16
    gemm_bt<0><<<gHB, TB, 0, stream>>>(xb, Dd, WpB + (size_t)t * Hh * Dd, Dd,
                                       bp + (size_t)t * Hh, nullptr, 0, 0, bufA, Hh, Dd);
    // h  = relu(a1 @ Wa^T + ba)                  [B,H] bf16
    gemm_bt<0><<<gHB, TB, 0, stream>>>(bufA, Hh, WaB, Hh,
                                       bop + (size_t)t * NO * Hh, idx + 2 * t, 0, Hh,
                                       bufB, Hh, Hh);
    // o  = relu(h @ Wb^T + bb)                   [B,H] bf16 (double relu collapses)
    gemm_bt<0><<<gHB, TB, 0, stream>>>(bufB, Hh, WbB, Hh,
                                       bop + (size_t)t * NO * Hh, idx + 2 * t, 1, Hh,
                                       bufA, Hh, Hh);
    // out (+)= o @ Wr[:, t*H:(t+1)*H]^T  (+ br at t=0)
    if (t == 0)
      gemm_bt<1><<<gOB, TB, 0, stream>>>(bufA, Hh, WrB + (size_t)t * Hh, Tt * Hh,
                                         br, nullptr, 0, 0, out, Oo, Hh);
    else
      gemm_bt<2><<<gOB, TB, 0, stream>>>(bufA, Hh, WrB + (size_t)t * Hh, Tt * Hh,
                                         nullptr, nullptr, 0, 0, out, Oo, Hh);
  }
}